// Round 1
// baseline (534.016 us; speedup 1.0000x reference)
//
#include <hip/hip_runtime.h>

// Dots1Attention on MI355X (gfx950).
// cvt3(fp32->bf16, fused) -> GEMM1(qkv; 256^2-tile 8-phase schedule; V written
//   transposed in epilogue) -> rmsnorm+rope -> flash attention -> GEMM2(128^2).
// GEMM1 now uses the m201-style 256x256/BK=64 8-wave 8-phase template:
//   per phase {ds_read subtile || stage one 16KiB half-tile via global_load_lds}
//   -> s_barrier -> lgkmcnt(0) -> setprio(1) + 16 MFMA + setprio(0) -> s_barrier,
//   counted s_waitcnt vmcnt(6) ONLY at phases 4 and 8 (3 half-tiles in flight,
//   never drained in the main loop). Ledger (derived + checked):
//   block k reads  Al@P1, Bh@P2, Ah@P3, Bl@P1&P4 (snake quadrant order
//   (0,0),(0,1),(1,1),(1,0) with A regs reused P1->P2, P3->P4; B-high P2->P3);
//   stages Bl(k+1)@P1, Al(k+2)@P2, Bh(k+2)@P3, Ah(k+2)@P4 — each exactly one
//   barrier-phase after its region's last read; vmcnt(6)@P4 retires everything
//   except {Al,Bh,Ah}(k+2). Tail clamps staged tile to 63 (idempotent dup
//   writes keep per-wave vmcnt ledger uniform).
// LDS chunk swizzle unchanged (phys chunk = logical ^ (row&7), pre-swizzled
// global source; 0 conflicts measured for this pattern). Accumulation order
// identical to previous kernel -> bit-identical numerics.

#define T_SEQ 2048
#define HID   4096
#define NH    32
#define NKVH  8
#define HD    128
#define QKVN  6144
#define QSZ   4096
#define QKN   5120   // qk buffer row stride (V not stored row-major)

typedef unsigned short u16;
typedef __attribute__((ext_vector_type(8))) short short8;
typedef __attribute__((ext_vector_type(4))) float floatx4;

__device__ __forceinline__ float bf2f(u16 u) {
  union { unsigned int i; float f; } c; c.i = ((unsigned int)u) << 16; return c.f;
}
__device__ __forceinline__ u16 f2bf(float f) {
  union { float f; unsigned int i; } c; c.f = f;
  unsigned int u = c.i;
  return (u16)((u + 0x7FFFu + ((u >> 16) & 1u)) >> 16);  // RNE
}
__device__ __forceinline__ floatx4 mfma16(short8 a, short8 b, floatx4 c) {
  return __builtin_amdgcn_mfma_f32_16x16x32_bf16(a, b, c, 0, 0, 0);
}

#define GLD16(g, l) __builtin_amdgcn_global_load_lds( \
    (__attribute__((address_space(1))) unsigned int*)(g), \
    (__attribute__((address_space(3))) unsigned int*)(l), 16, 0, 0)

// ---------------------------------------------------------------- cvt f32->bf16 x3
__global__ __launch_bounds__(256) void cvt3_kernel(
    const float* __restrict__ s0, const float* __restrict__ s1,
    const float* __restrict__ s2, u16* __restrict__ d0, u16* __restrict__ d1,
    u16* __restrict__ d2, int n0, int n1, int n2) {
  int total = n0 + n1 + n2;
  int stride = gridDim.x * 256;
  for (int i = blockIdx.x * 256 + threadIdx.x; i < total; i += stride) {
    const float* s; u16* d; int j = i;
    if (j < n0)           { s = s0; d = d0; }
    else if (j < n0 + n1) { j -= n0; s = s1; d = d1; }
    else                  { j -= n0 + n1; s = s2; d = d2; }
    float4 v = ((const float4*)s)[j];
    ushort4 o;
    o.x = f2bf(v.x); o.y = f2bf(v.y); o.z = f2bf(v.z); o.w = f2bf(v.w);
    ((ushort4*)d)[j] = o;
  }
}

// ---------------------------------------------------------------- GEMM  C = A * B^T
// (128x128 tile m97-structure; used for GEMM2 only now.)
// LDS layout: per 128-row tile, row m has 8 chunks of 8 bf16; logical chunk c
// lives at physical slot c ^ (m&7). Bank-uniform for GLD16 + ds_read_b128.
template <int MODE>
__global__ __launch_bounds__(256, 2) void gemm_bt(const u16* __restrict__ A,
    const u16* __restrict__ B, void* __restrict__ Cv, u16* __restrict__ VT,
    int mtiles, int K, int ldC) {
  __shared__ __attribute__((aligned(16))) u16 As[128 * 64];
  __shared__ __attribute__((aligned(16))) u16 Bs[128 * 64];
  const int tid = threadIdx.x;
  const int wave = tid >> 6, lane = tid & 63;
  const int lq = lane >> 4, lc = lane & 15;
  const int wm = wave >> 1, wn = wave & 1;
  // XCD-aware bijective swizzle (grid % 8 == 0), then col-major decompose
  // (consecutive ids share the B tile -> per-XCD L2 locality).
  const int id = ((int)blockIdx.x & 7) * ((int)gridDim.x >> 3) + ((int)blockIdx.x >> 3);
  const int by = id % mtiles, bx = id / mtiles;
  const int m0 = by * 128, n0 = bx * 128;

  floatx4 acc[4][4];
#pragma unroll
  for (int i = 0; i < 4; ++i)
#pragma unroll
    for (int j = 0; j < 4; ++j) acc[i][j] = {0.f, 0.f, 0.f, 0.f};

  int arow[4], brow[4];
#pragma unroll
  for (int i = 0; i < 4; ++i) {
    arow[i] = wm * 64 + i * 16 + lc;
    brow[i] = wn * 64 + i * 16 + lc;
  }

  const u16* asrc[4]; const u16* bsrc[4];
#pragma unroll
  for (int r = 0; r < 4; ++r) {
    int L = r * 256 + tid;
    int mm = L >> 3;
    int cc = (L & 7) ^ (mm & 7);
    asrc[r] = A + (size_t)(m0 + mm) * K + cc * 8;
    bsrc[r] = B + (size_t)(n0 + mm) * K + cc * 8;
  }

  for (int k0 = 0; k0 < K; k0 += 64) {
#pragma unroll
    for (int r = 0; r < 4; ++r) {
      GLD16(asrc[r] + k0, As + (r * 256 + wave * 64) * 8);
      GLD16(bsrc[r] + k0, Bs + (r * 256 + wave * 64) * 8);
    }
    __syncthreads();
#pragma unroll
    for (int kb = 0; kb < 2; ++kb) {
      short8 af[4], bfr[4];
#pragma unroll
      for (int mi = 0; mi < 4; ++mi)
        af[mi] = *(const short8*)&As[arow[mi] * 64 + (((kb * 4 + lq) ^ (arow[mi] & 7)) * 8)];
#pragma unroll
      for (int ni = 0; ni < 4; ++ni)
        bfr[ni] = *(const short8*)&Bs[brow[ni] * 64 + (((kb * 4 + lq) ^ (brow[ni] & 7)) * 8)];
#pragma unroll
      for (int mi = 0; mi < 4; ++mi)
#pragma unroll
        for (int ni = 0; ni < 4; ++ni)
          acc[mi][ni] = mfma16(af[mi], bfr[ni], acc[mi][ni]);
    }
    __syncthreads();
  }

  // C/D layout: row = lq*4 + r, col = lc (m89/m91-verified)
  if (MODE == 1 && n0 >= 5120) {  // V heads -> VT[kvh][d][t], 4 t packed
#pragma unroll
    for (int mi = 0; mi < 4; ++mi) {
      int row = m0 + wm * 64 + mi * 16 + lq * 4;
#pragma unroll
      for (int ni = 0; ni < 4; ++ni) {
        int rel = n0 + wn * 64 + ni * 16 + lc - 5120;
        ushort4 u;
        u.x = f2bf(acc[mi][ni][0]); u.y = f2bf(acc[mi][ni][1]);
        u.z = f2bf(acc[mi][ni][2]); u.w = f2bf(acc[mi][ni][3]);
        *(ushort4*)&VT[(size_t)rel * T_SEQ + row] = u;
      }
    }
  } else {
#pragma unroll
    for (int mi = 0; mi < 4; ++mi) {
      int row = m0 + wm * 64 + mi * 16 + lq * 4;
#pragma unroll
      for (int ni = 0; ni < 4; ++ni) {
        int col = n0 + wn * 64 + ni * 16 + lc;
#pragma unroll
        for (int r = 0; r < 4; ++r) {
          if (MODE == 1)
            ((u16*)Cv)[(size_t)(row + r) * ldC + col] = f2bf(acc[mi][ni][r]);
          else
            ((float*)Cv)[(size_t)(row + r) * ldC + col] = acc[mi][ni][r];
        }
      }
    }
  }
}

// ---------------------------------------------------------------- GEMM1: 256^2 8-phase
// A[2048][4096] bf16, B[6144][4096] bf16, C = A*B^T. Grid 192 x 512 threads.
// 8 waves (2M x 4N), per-wave 128x64 output, acc[8][4] floatx4.
// Halves: Al = rows [0,64)u[128,192), Ah = +64; Bl = {wn*64+[0,32)}, Bh = +32.
#define SGA(BUF, H, S) do { \
    GLD16(apt[H][0] + (size_t)(S) * 64, As + (BUF) * 16384 + aoff[H][0]); \
    GLD16(apt[H][1] + (size_t)(S) * 64, As + (BUF) * 16384 + aoff[H][1]); \
  } while (0)
#define SGB(BUF, H, S) do { \
    GLD16(bpt[H][0] + (size_t)(S) * 64, Bs + (BUF) * 16384 + boff[H][0]); \
    GLD16(bpt[H][1] + (size_t)(S) * 64, Bs + (BUF) * 16384 + boff[H][1]); \
  } while (0)
#define VM6 asm volatile("s_waitcnt vmcnt(6)" ::: "memory")

#define PH(BUF, QM, QN, LA, LB, STAGE, VMW) do { \
    if (LA) { \
      _Pragma("unroll") for (int mi = 0; mi < 4; ++mi) { \
        const u16* ap = As + (BUF) * 16384 + abase + ((QM) * 64 + mi * 16) * 64; \
        af[mi][0] = *(const short8*)(ap + c0); \
        af[mi][1] = *(const short8*)(ap + c1); \
      } \
    } \
    if (LB) { \
      _Pragma("unroll") for (int ni = 0; ni < 2; ++ni) { \
        const u16* bp = Bs + (BUF) * 16384 + bbase + ((QN) * 32 + ni * 16) * 64; \
        bfr[ni][0] = *(const short8*)(bp + c0); \
        bfr[ni][1] = *(const short8*)(bp + c1); \
      } \
    } \
    STAGE; \
    __builtin_amdgcn_s_barrier(); \
    asm volatile("s_waitcnt lgkmcnt(0)"); \
    __builtin_amdgcn_s_setprio(1); \
    _Pragma("unroll") for (int mi = 0; mi < 4; ++mi) \
      _Pragma("unroll") for (int ni = 0; ni < 2; ++ni) { \
        acc[(QM) * 4 + mi][(QN) * 2 + ni] = \
            mfma16(af[mi][0], bfr[ni][0], acc[(QM) * 4 + mi][(QN) * 2 + ni]); \
        acc[(QM) * 4 + mi][(QN) * 2 + ni] = \
            mfma16(af[mi][1], bfr[ni][1], acc[(QM) * 4 + mi][(QN) * 2 + ni]); \
      } \
    __builtin_amdgcn_s_setprio(0); \
    VMW; \
    __builtin_amdgcn_s_barrier(); \
  } while (0)

__global__ __launch_bounds__(512, 2) void gemm1_8ph(const u16* __restrict__ A,
    const u16* __restrict__ B, u16* __restrict__ C, u16* __restrict__ VT) {
  __shared__ __attribute__((aligned(16))) u16 As[2 * 256 * 64];  // 64 KiB
  __shared__ __attribute__((aligned(16))) u16 Bs[2 * 256 * 64];  // 64 KiB
  const int tid = threadIdx.x;
  const int wave = tid >> 6, lane = tid & 63;
  const int lq = lane >> 4, lc = lane & 15;
  const int wm = wave >> 2, wn = wave & 3;
  // XCD swizzle: 192 blocks, 24 per XCD; col-major decompose (by fastest).
  const int id = ((int)blockIdx.x & 7) * 24 + ((int)blockIdx.x >> 3);
  const int by = id & 7, bx = id >> 3;
  const int m0 = by * 256, n0 = bx * 256;

  floatx4 acc[8][4];
#pragma unroll
  for (int i = 0; i < 8; ++i)
#pragma unroll
    for (int j = 0; j < 4; ++j) acc[i][j] = {0.f, 0.f, 0.f, 0.f};

  // ds_read addressing: row = (wm*128 or wn*64) + q*{64,32} + f*16 + lc;
  // row&7 == lc&7, so the swizzled chunk offsets are per-thread constants.
  const int c0 = (lq ^ (lc & 7)) * 8;
  const int c1 = ((4 + lq) ^ (lc & 7)) * 8;
  const int abase = (wm * 128 + lc) * 64;
  const int bbase = (wn * 64 + lc) * 64;

  // staging: each wave stages 2 x 8-row blocks per half (2 GLD16 / half).
  const int srow = lane >> 3;                    // row within 8-row block
  const int schunk = ((lane & 7) ^ srow) * 8;    // pre-swizzled source chunk
  const u16* apt[2][2]; const u16* bpt[2][2];
  int aoff[2][2], boff[2][2];
#pragma unroll
  for (int h = 0; h < 2; ++h)
#pragma unroll
    for (int i = 0; i < 2; ++i) {
      int idx = wave * 2 + i;
      int rba = (idx & 7) + (idx >> 3) * 16 + h * 8;   // A rowblocks
      int rbb = (idx & 3) + (idx >> 2) * 8 + h * 4;    // B rowblocks
      apt[h][i] = A + (size_t)(m0 + rba * 8 + srow) * HID + schunk;
      bpt[h][i] = B + (size_t)(n0 + rbb * 8 + srow) * HID + schunk;
      aoff[h][i] = rba * 512;
      boff[h][i] = rbb * 512;
    }

  // prologue: Al(0) Bl(0) Bh(0) Ah(0) Al(1) Bh(1) Ah(1); keep last 3 in flight.
  SGA(0, 0, 0); SGB(0, 0, 0); SGB(0, 1, 0); SGA(0, 1, 0);
  SGA(1, 0, 1); SGB(1, 1, 1); SGA(1, 1, 1);
  VM6;
  __builtin_amdgcn_s_barrier();

  short8 af[4][2];
  short8 bfr[2][2];
  for (int j = 0; j < 64; j += 2) {
    const int s2 = (j + 2 < 63) ? j + 2 : 63;
    const int s3 = (j + 3 < 63) ? j + 3 : 63;
    // block j (buf0): quadrants (0,0),(0,1),(1,1),(1,0)
    PH(0, 0, 0, 1, 1, SGB(1, 0, j + 1), (void)0);  // stage Bl(j+1)->buf1
    PH(0, 0, 1, 0, 1, SGA(0, 0, s2),    (void)0);  // stage Al(j+2)->buf0
    PH(0, 1, 1, 1, 0, SGB(0, 1, s2),    (void)0);  // stage Bh(j+2)->buf0
    PH(0, 1, 0, 0, 1, SGA(0, 1, s2),    VM6);      // stage Ah(j+2)->buf0
    // block j+1 (buf1)
    PH(1, 0, 0, 1, 1, SGB(0, 0, s2),    (void)0);  // stage Bl(j+2)->buf0
    PH(1, 0, 1, 0, 1, SGA(1, 0, s3),    (void)0);  // stage Al(j+3)->buf1
    PH(1, 1, 1, 1, 0, SGB(1, 1, s3),    (void)0);  // stage Bh(j+3)->buf1
    PH(1, 1, 0, 0, 1, SGA(1, 1, s3),    VM6);      // stage Ah(j+3)->buf1
  }

  asm volatile("s_waitcnt vmcnt(0)" ::: "memory");  // drain tail dup-stages

  // C/D layout: row = lq*4 + r, col = lc
  if (n0 >= 5120) {  // V heads -> VT[kvh][d][t], 4 t packed
#pragma unroll
    for (int mi = 0; mi < 8; ++mi) {
      int row = m0 + wm * 128 + mi * 16 + lq * 4;
#pragma unroll
      for (int ni = 0; ni < 4; ++ni) {
        int rel = n0 + wn * 64 + ni * 16 + lc - 5120;
        ushort4 u;
        u.x = f2bf(acc[mi][ni][0]); u.y = f2bf(acc[mi][ni][1]);
        u.z = f2bf(acc[mi][ni][2]); u.w = f2bf(acc[mi][ni][3]);
        *(ushort4*)&VT[(size_t)rel * T_SEQ + row] = u;
      }
    }
  } else {
#pragma unroll
    for (int mi = 0; mi < 8; ++mi) {
      int row = m0 + wm * 128 + mi * 16 + lq * 4;
#pragma unroll
      for (int ni = 0; ni < 4; ++ni) {
        int col = n0 + wn * 64 + ni * 16 + lc;
#pragma unroll
        for (int r = 0; r < 4; ++r)
          C[(size_t)(row + r) * QKN + col] = f2bf(acc[mi][ni][r]);
      }
    }
  }
}

// ---------------------------------------------------------------- RMSNorm + RoPE
// grid (T, 10), block 256: wave w handles head-slot blockIdx.y*4+w (0..31 q, 32..39 k).
// Lane l owns dims l, l+64 (the RoPE rotate pair). Q also scaled by 1/sqrt(HD).
__global__ __launch_bounds__(256) void norm_rope_kernel(const u16* __restrict__ qk,
    const float* __restrict__ qw, const float* __restrict__ kw,
    u16* __restrict__ Qo, u16* __restrict__ Ko) {
  const int t = blockIdx.x;
  const int hs = blockIdx.y * 4 + (threadIdx.x >> 6);
  const int l = threadIdx.x & 63;
  const bool isq = hs < NH;
  const int col0 = isq ? hs * HD : QSZ + (hs - NH) * HD;
  const u16* src = qk + (size_t)t * QKN + col0;
  float x1 = bf2f(src[l]);
  float x2 = bf2f(src[l + 64]);
  float ss = x1 * x1 + x2 * x2;
#pragma unroll
  for (int m = 1; m < 64; m <<= 1) ss += __shfl_xor(ss, m);
  float rstd = rsqrtf(ss * (1.0f / HD) + 1e-6f);
  const float* w = isq ? qw : kw;
  float n1 = x1 * rstd * w[l];
  float n2 = x2 * rstd * w[l + 64];
  float inv = exp2f((float)l * -0.20762050593045158f);  // 10000^(-l/64)
  float ang = (float)t * inv;
  float s, c;
  __sincosf(ang, &s, &c);
  float o1 = n1 * c - n2 * s;
  float o2 = n2 * c + n1 * s;
  if (isq) {
    o1 *= 0.08838834764831845f; o2 *= 0.08838834764831845f;  // 1/sqrt(128)
    u16* dst = Qo + ((size_t)hs * T_SEQ + t) * HD;
    dst[l] = f2bf(o1); dst[l + 64] = f2bf(o2);
  } else {
    u16* dst = Ko + ((size_t)(hs - NH) * T_SEQ + t) * HD;
    dst[l] = f2bf(o1); dst[l + 64] = f2bf(o2);
  }
}

// ---------------------------------------------------------------- flash attention
// (unchanged — no counters yet; revisit once it re-surfaces in top-5)
__global__ __launch_bounds__(256, 2) void attn_kernel(const u16* __restrict__ Qg,
    const u16* __restrict__ Kg, const u16* __restrict__ VTg, u16* __restrict__ Og) {
  __shared__ __attribute__((aligned(16))) u16 Ks[8192];
  __shared__ __attribute__((aligned(16))) u16 Vs[2][8192];
  __shared__ __attribute__((aligned(16))) u16 Ps[8192];

  const int bid = blockIdx.x;
  const int h = bid & 31;
  const int qq = bid >> 5;
  const int qt = (qq < 8) ? (15 - qq) : (qq - 8);
  const int kvh = h >> 2;
  const int tid = threadIdx.x;
  const int wave = tid >> 6, lane = tid & 63;
  const int lq = lane >> 4, lc = lane & 15;

  const u16* kbase[4];
  const u16* vbase[4];
#pragma unroll
  for (int i = 0; i < 4; ++i) {
    int L = i * 256 + tid;
    int s = L >> 4, cp = L & 15;
    kbase[i] = Kg + ((size_t)kvh * T_SEQ + s) * HD + ((cp ^ (s & 15)) * 8);
    int d = L >> 3, cv = L & 7;
    vbase[i] = VTg + ((size_t)kvh * HD + d) * T_SEQ + ((cv ^ (d & 7)) * 8);
  }

  short8 qf[2][4];
#pragma unroll
  for (int mb = 0; mb < 2; ++mb)
#pragma unroll
    for (int ks = 0; ks < 4; ++ks) {
      int t = qt * 128 + wave * 32 + mb * 16 + lc;
      qf[mb][ks] = *(const short8*)&Qg[((size_t)h * T_SEQ + t) * HD + ks * 32 + lq * 8];
    }

  short8 ones;
#pragma unroll
  for (int j = 0; j < 8; ++j) ones[j] = (short)0x3F80;  // bf16 1.0

  floatx4 of[2][8];
  floatx4 lacc[2];
#pragma unroll
  for (int mb = 0; mb < 2; ++mb) {
    lacc[mb] = {0.f, 0.f, 0.f, 0.f};
#pragma unroll
    for (int db = 0; db < 8; ++db) of[mb][db] = {0.f, 0.f, 0.f, 0.f};
  }

  const int ktmax = 2 * qt + 1;
  const int t0g = qt * 128 + wave * 32;
  const int wave_tmax = t0g + 31;

#pragma unroll
  for (int i = 0; i < 4; ++i) {
    GLD16(kbase[i], Ks + (i * 256 + wave * 64) * 8);
    GLD16(vbase[i], Vs[0] + (i * 256 + wave * 64) * 8);
  }

  for (int kt = 0; kt <= ktmax; ++kt) {
    __syncthreads();
    if (kt + 1 <= ktmax) {
      u16* vd = Vs[(kt + 1) & 1] + (size_t)wave * 64 * 8;
#pragma unroll
      for (int i = 0; i < 4; ++i)
        GLD16(vbase[i] + (kt + 1) * 64, vd + i * 256 * 8);
    }
    const bool active = (kt * 64) <= wave_tmax;
    if (active) {
      floatx4 sf[2][4];
#pragma unroll
      for (int mb = 0; mb < 2; ++mb)
#pragma unroll
        for (int nb = 0; nb < 4; ++nb) sf[mb][nb] = {0.f, 0.f, 0.f, 0.f};
#pragma unroll
      for (int ks = 0; ks < 4; ++ks) {
        short8 kf[4];
#pragma unroll
        for (int nb = 0; nb < 4; ++nb)
          kf[nb] = *(const short8*)&Ks[(nb * 16 + lc) * 128 + ((4 * ks + lq) ^ lc) * 8];
#pragma unroll
        for (int mb = 0; mb < 2; ++mb)
#pragma unroll
          for (int nb = 0; nb < 4; ++nb)
            sf[mb][nb] = mfma16(kf[nb], qf[mb][ks], sf[mb][nb]);
      }
      const bool nm = (kt * 64 + 63) > t0g;
#pragma unroll
      for (int mb = 0; mb < 2; ++mb) {
        const int trow = wave * 32 + mb * 16 + lc;
        const int tg = qt * 128 + trow;
#pragma unroll
        for (int nb = 0; nb < 4; ++nb) {
          ushort4 u;
          float p0 = __expf(sf[mb][nb][0]);
          float p1 = __expf(sf[mb][nb][1]);
          float p2 = __expf(sf[mb][nb][2]);
          float p3 = __expf(sf[mb][nb][3]);
          if (nm) {
            int sg = kt * 64 + nb * 16 + lq * 4;
            p0 = (sg + 0 <= tg) ? p0 : 0.f;
            p1 = (sg + 1 <= tg) ? p1 : 0.f;
            p2 = (sg + 2 <= tg) ? p2 : 0.f;
            p3 = (sg + 3 <= tg) ? p3 : 0.f;
          }
          u.x = f2bf(p0); u.y = f2bf(p1); u.z = f2bf(p2); u.w = f2bf(p3);
          int c = 2 * nb + (lq >> 1);
          *(ushort4*)&Ps[trow * 64 + ((c ^ (trow & 7)) * 8) + (lq & 1) * 4] = u;
        }
      }
    }
    __syncthreads();
    if (kt + 1 <= ktmax) {
      u16* kd = Ks + (size_t)wave * 64 * 8;
#pragma unroll
      for (int i = 0; i < 4; ++i)
        GLD16(kbase[i] + (size_t)(kt + 1) * 8192, kd + i * 256 * 8);
    }
    if (active) {
      const u16* vb = Vs[kt & 1];
      short8 pf[2][2];
#pragma unroll
      for (int mb = 0; mb < 2; ++mb)
#pragma unroll
        for (int k2 = 0; k2 < 2; ++k2) {
          int trow = wave * 32 + mb * 16 + lc;
          pf[mb][k2] =
              *(const short8*)&Ps[trow * 64 + (((4 * k2 + lq) ^ (lc & 7)) * 8)];
        }
#pragma unroll
      for (int k2 = 0; k2 < 2; ++k2) {
#pragma unroll
        for (int db = 0; db < 8; ++db) {
          short8 vf =
              *(const short8*)&vb[(db * 16 + lc) * 64 + (((4 * k2 + lq) ^ (lc & 7)) * 8)];
          of[0][db] = mfma16(pf[0][k2], vf, of[0][db]);
          of[1][db] = mfma16(pf[1][k2], vf, of[1][db]);
        }
        lacc[0] = mfma16(pf[0][k2], ones, lacc[0]);
        lacc[1] = mfma16(pf[1][k2], ones, lacc[1]);
      }
    }
  }
#pragma unroll
  for (int mb = 0; mb < 2; ++mb)
#pragma unroll
    for (int r = 0; r < 4; ++r) {
      float inv = 1.f / lacc[mb][r];
      int tg = qt * 128 + wave * 32 + mb * 16 + lq * 4 + r;
#pragma unroll
      for (int db = 0; db < 8; ++db)
        Og[(size_t)tg * QSZ + h * HD + db * 16 + lc] = f2bf(of[mb][db][r] * inv);
    }
}

// ---------------------------------------------------------------- launcher
extern "C" void kernel_launch(void* const* d_in, const int* in_sizes, int n_in,
                              void* d_out, int out_size, void* d_ws, size_t ws_size,
                              hipStream_t stream) {
  (void)in_sizes; (void)n_in; (void)out_size; (void)ws_size;
  const float* hidden = (const float*)d_in[1];
  const float* wqkv   = (const float*)d_in[2];
  const float* wo     = (const float*)d_in[3];
  const float* qw     = (const float*)d_in[4];
  const float* kw     = (const float*)d_in[5];
  float* out = (float*)d_out;
  char* ws = (char*)d_ws;

  // workspace (lifetime-aliased):
  //  [0,16M)    h_bf (dead after GEMM1)  -> attn_bf
  //  [16M,64M)  wq_bf (dead after GEMM1) -> q_bf [16M,32M), k_bf [32M,36M)
  //  [64M,96M)  wo_bf (persists to GEMM2)
  //  [96M,100M) vT_bf (written by GEMM1 epilogue)
  //  [100M,120M) qk_bf (dead after norm_rope)
  u16* h_bf    = (u16*)(ws + 0);
  u16* wq_bf   = (u16*)(ws + 16777216);
  u16* wo_bf   = (u16*)(ws + 67108864);
  u16* vT_bf   = (u16*)(ws + 100663296);
  u16* qk_bf   = (u16*)(ws + 104857600);
  u16* q_bf    = (u16*)(ws + 16777216);
  u16* k_bf    = (u16*)(ws + 33554432);
  u16* attn_bf = (u16*)(ws + 0);

  cvt3_kernel<<<8192, 256, 0, stream>>>(
      hidden, wqkv, wo, h_bf, wq_bf, wo_bf,
      T_SEQ * HID / 4, QKVN * HID / 4, HID * QSZ / 4);

  gemm1_8ph<<<192, 512, 0, stream>>>(h_bf, wq_bf, qk_bf, vT_bf);

  norm_rope_kernel<<<dim3(T_SEQ, 10), 256, 0, stream>>>(
      qk_bf, qw, kw, q_bf, k_bf);

  attn_kernel<<<512, 256, 0, stream>>>(q_bf, k_bf, vT_bf, attn_bf);

  gemm_bt<0><<<512, 256, 0, stream>>>(attn_bf, wo_bf, out, vT_bf,
                                      T_SEQ / 128, HID, QSZ);
}

// Round 2
// 529.125 us; speedup vs baseline: 1.0092x; 1.0092x over previous
//
#include <hip/hip_runtime.h>

// Dots1Attention on MI355X (gfx950).
// cvt3(fp32->bf16, fused) -> GEMM1(qkv; 256^2-tile 8-phase schedule; V written
//   transposed in epilogue) -> rmsnorm+rope -> flash attention -> GEMM2(128^2).
// GEMM1: m201-style 256x256/BK=64 8-wave 8-phase template. R1 measured 626 TF
// (MfmaUtil 25%) because nothing pinned the schedule: raw s_barrier has no
// memory semantics in LLVM IR, so the compiler sank the ds_reads past the
// barrier to their MFMA uses, serializing每phase. R2 adds sched_barrier(0)
// pins (HK technique #4) + "memory" clobbers + lgkmcnt(8) throttle on the
// 12-read phases. Schedule/ledger/numerics identical to R1 (which passed).
//   Ledger: block k reads Al@P1, Bh@P2, Ah@P3, Bl@P1&P4 (snake quadrants
//   (0,0),(0,1),(1,1),(1,0); A regs reused P1->P2, P3->P4; B-high P2->P3);
//   stages Bl(k+1)@P1, Al(k+2)@P2, Bh(k+2)@P3, Ah(k+2)@P4 — each one
//   barrier-phase after its region's last read; vmcnt(6) only at P4/P8
//   (3 half-tiles always in flight). Tail clamps staged tile to 63
//   (idempotent dup writes keep the per-wave vmcnt ledger uniform).

#define T_SEQ 2048
#define HID   4096
#define NH    32
#define NKVH  8
#define HD    128
#define QKVN  6144
#define QSZ   4096
#define QKN   5120   // qk buffer row stride (V not stored row-major)

typedef unsigned short u16;
typedef __attribute__((ext_vector_type(8))) short short8;
typedef __attribute__((ext_vector_type(4))) float floatx4;

__device__ __forceinline__ float bf2f(u16 u) {
  union { unsigned int i; float f; } c; c.i = ((unsigned int)u) << 16; return c.f;
}
__device__ __forceinline__ u16 f2bf(float f) {
  union { float f; unsigned int i; } c; c.f = f;
  unsigned int u = c.i;
  return (u16)((u + 0x7FFFu + ((u >> 16) & 1u)) >> 16);  // RNE
}
__device__ __forceinline__ floatx4 mfma16(short8 a, short8 b, floatx4 c) {
  return __builtin_amdgcn_mfma_f32_16x16x32_bf16(a, b, c, 0, 0, 0);
}

#define GLD16(g, l) __builtin_amdgcn_global_load_lds( \
    (__attribute__((address_space(1))) unsigned int*)(g), \
    (__attribute__((address_space(3))) unsigned int*)(l), 16, 0, 0)

// ---------------------------------------------------------------- cvt f32->bf16 x3
__global__ __launch_bounds__(256) void cvt3_kernel(
    const float* __restrict__ s0, const float* __restrict__ s1,
    const float* __restrict__ s2, u16* __restrict__ d0, u16* __restrict__ d1,
    u16* __restrict__ d2, int n0, int n1, int n2) {
  int total = n0 + n1 + n2;
  int stride = gridDim.x * 256;
  for (int i = blockIdx.x * 256 + threadIdx.x; i < total; i += stride) {
    const float* s; u16* d; int j = i;
    if (j < n0)           { s = s0; d = d0; }
    else if (j < n0 + n1) { j -= n0; s = s1; d = d1; }
    else                  { j -= n0 + n1; s = s2; d = d2; }
    float4 v = ((const float4*)s)[j];
    ushort4 o;
    o.x = f2bf(v.x); o.y = f2bf(v.y); o.z = f2bf(v.z); o.w = f2bf(v.w);
    ((ushort4*)d)[j] = o;
  }
}

// ---------------------------------------------------------------- GEMM  C = A * B^T
// (128x128 tile m97-structure; used for GEMM2 only now.)
template <int MODE>
__global__ __launch_bounds__(256, 2) void gemm_bt(const u16* __restrict__ A,
    const u16* __restrict__ B, void* __restrict__ Cv, u16* __restrict__ VT,
    int mtiles, int K, int ldC) {
  __shared__ __attribute__((aligned(16))) u16 As[128 * 64];
  __shared__ __attribute__((aligned(16))) u16 Bs[128 * 64];
  const int tid = threadIdx.x;
  const int wave = tid >> 6, lane = tid & 63;
  const int lq = lane >> 4, lc = lane & 15;
  const int wm = wave >> 1, wn = wave & 1;
  const int id = ((int)blockIdx.x & 7) * ((int)gridDim.x >> 3) + ((int)blockIdx.x >> 3);
  const int by = id % mtiles, bx = id / mtiles;
  const int m0 = by * 128, n0 = bx * 128;

  floatx4 acc[4][4];
#pragma unroll
  for (int i = 0; i < 4; ++i)
#pragma unroll
    for (int j = 0; j < 4; ++j) acc[i][j] = {0.f, 0.f, 0.f, 0.f};

  int arow[4], brow[4];
#pragma unroll
  for (int i = 0; i < 4; ++i) {
    arow[i] = wm * 64 + i * 16 + lc;
    brow[i] = wn * 64 + i * 16 + lc;
  }

  const u16* asrc[4]; const u16* bsrc[4];
#pragma unroll
  for (int r = 0; r < 4; ++r) {
    int L = r * 256 + tid;
    int mm = L >> 3;
    int cc = (L & 7) ^ (mm & 7);
    asrc[r] = A + (size_t)(m0 + mm) * K + cc * 8;
    bsrc[r] = B + (size_t)(n0 + mm) * K + cc * 8;
  }

  for (int k0 = 0; k0 < K; k0 += 64) {
#pragma unroll
    for (int r = 0; r < 4; ++r) {
      GLD16(asrc[r] + k0, As + (r * 256 + wave * 64) * 8);
      GLD16(bsrc[r] + k0, Bs + (r * 256 + wave * 64) * 8);
    }
    __syncthreads();
#pragma unroll
    for (int kb = 0; kb < 2; ++kb) {
      short8 af[4], bfr[4];
#pragma unroll
      for (int mi = 0; mi < 4; ++mi)
        af[mi] = *(const short8*)&As[arow[mi] * 64 + (((kb * 4 + lq) ^ (arow[mi] & 7)) * 8)];
#pragma unroll
      for (int ni = 0; ni < 4; ++ni)
        bfr[ni] = *(const short8*)&Bs[brow[ni] * 64 + (((kb * 4 + lq) ^ (brow[ni] & 7)) * 8)];
#pragma unroll
      for (int mi = 0; mi < 4; ++mi)
#pragma unroll
        for (int ni = 0; ni < 4; ++ni)
          acc[mi][ni] = mfma16(af[mi], bfr[ni], acc[mi][ni]);
    }
    __syncthreads();
  }

  if (MODE == 1 && n0 >= 5120) {  // V heads -> VT[kvh][d][t], 4 t packed
#pragma unroll
    for (int mi = 0; mi < 4; ++mi) {
      int row = m0 + wm * 64 + mi * 16 + lq * 4;
#pragma unroll
      for (int ni = 0; ni < 4; ++ni) {
        int rel = n0 + wn * 64 + ni * 16 + lc - 5120;
        ushort4 u;
        u.x = f2bf(acc[mi][ni][0]); u.y = f2bf(acc[mi][ni][1]);
        u.z = f2bf(acc[mi][ni][2]); u.w = f2bf(acc[mi][ni][3]);
        *(ushort4*)&VT[(size_t)rel * T_SEQ + row] = u;
      }
    }
  } else {
#pragma unroll
    for (int mi = 0; mi < 4; ++mi) {
      int row = m0 + wm * 64 + mi * 16 + lq * 4;
#pragma unroll
      for (int ni = 0; ni < 4; ++ni) {
        int col = n0 + wn * 64 + ni * 16 + lc;
#pragma unroll
        for (int r = 0; r < 4; ++r) {
          if (MODE == 1)
            ((u16*)Cv)[(size_t)(row + r) * ldC + col] = f2bf(acc[mi][ni][r]);
          else
            ((float*)Cv)[(size_t)(row + r) * ldC + col] = acc[mi][ni][r];
        }
      }
    }
  }
}

// ---------------------------------------------------------------- GEMM1: 256^2 8-phase
#define SGA(BUF, H, S) do { \
    GLD16(apt[H][0] + (size_t)(S) * 64, As + (BUF) * 16384 + aoff[H][0]); \
    GLD16(apt[H][1] + (size_t)(S) * 64, As + (BUF) * 16384 + aoff[H][1]); \
  } while (0)
#define SGB(BUF, H, S) do { \
    GLD16(bpt[H][0] + (size_t)(S) * 64, Bs + (BUF) * 16384 + boff[H][0]); \
    GLD16(bpt[H][1] + (size_t)(S) * 64, Bs + (BUF) * 16384 + boff[H][1]); \
  } while (0)
#define VM6 asm volatile("s_waitcnt vmcnt(6)" ::: "memory")
#define LG8 asm volatile("s_waitcnt lgkmcnt(8)" ::: "memory")
#define SB0 __builtin_amdgcn_sched_barrier(0)

// Phase: {ds_read subtile || stage} pinned above barrier-1; lgkmcnt(0)+pin
// (rule #18); setprio'd MFMA cluster; pin; counted vmcnt; barrier-2.
#define PH(BUF, QM, QN, LA, LB, STAGE, LGK, VMW) do { \
    if (LA) { \
      _Pragma("unroll") for (int mi = 0; mi < 4; ++mi) { \
        const u16* ap = As + (BUF) * 16384 + abase + ((QM) * 64 + mi * 16) * 64; \
        af[mi][0] = *(const short8*)(ap + c0); \
        af[mi][1] = *(const short8*)(ap + c1); \
      } \
    } \
    if (LB) { \
      _Pragma("unroll") for (int ni = 0; ni < 2; ++ni) { \
        const u16* bp = Bs + (BUF) * 16384 + bbase + ((QN) * 32 + ni * 16) * 64; \
        bfr[ni][0] = *(const short8*)(bp + c0); \
        bfr[ni][1] = *(const short8*)(bp + c1); \
      } \
    } \
    STAGE; \
    SB0; \
    LGK; \
    __builtin_amdgcn_s_barrier(); \
    asm volatile("s_waitcnt lgkmcnt(0)" ::: "memory"); \
    SB0; \
    __builtin_amdgcn_s_setprio(1); \
    _Pragma("unroll") for (int mi = 0; mi < 4; ++mi) \
      _Pragma("unroll") for (int ni = 0; ni < 2; ++ni) { \
        acc[(QM) * 4 + mi][(QN) * 2 + ni] = \
            mfma16(af[mi][0], bfr[ni][0], acc[(QM) * 4 + mi][(QN) * 2 + ni]); \
        acc[(QM) * 4 + mi][(QN) * 2 + ni] = \
            mfma16(af[mi][1], bfr[ni][1], acc[(QM) * 4 + mi][(QN) * 2 + ni]); \
      } \
    __builtin_amdgcn_s_setprio(0); \
    SB0; \
    VMW; \
    __builtin_amdgcn_s_barrier(); \
  } while (0)

__global__ __launch_bounds__(512, 2) void gemm1_8ph(const u16* __restrict__ A,
    const u16* __restrict__ B, u16* __restrict__ C, u16* __restrict__ VT) {
  __shared__ __attribute__((aligned(16))) u16 As[2 * 256 * 64];  // 64 KiB
  __shared__ __attribute__((aligned(16))) u16 Bs[2 * 256 * 64];  // 64 KiB
  const int tid = threadIdx.x;
  const int wave = tid >> 6, lane = tid & 63;
  const int lq = lane >> 4, lc = lane & 15;
  const int wm = wave >> 2, wn = wave & 3;
  // XCD swizzle: 192 blocks, 24 per XCD; col-major decompose (by fastest).
  const int id = ((int)blockIdx.x & 7) * 24 + ((int)blockIdx.x >> 3);
  const int by = id & 7, bx = id >> 3;
  const int m0 = by * 256, n0 = bx * 256;

  floatx4 acc[8][4];
#pragma unroll
  for (int i = 0; i < 8; ++i)
#pragma unroll
    for (int j = 0; j < 4; ++j) acc[i][j] = {0.f, 0.f, 0.f, 0.f};

  // ds_read addressing: row&7 == lc&7, so swizzled chunk offsets are constants.
  const int c0 = (lq ^ (lc & 7)) * 8;
  const int c1 = ((4 + lq) ^ (lc & 7)) * 8;
  const int abase = (wm * 128 + lc) * 64;
  const int bbase = (wn * 64 + lc) * 64;

  // staging: each wave stages 2 x 8-row blocks per half (2 GLD16 / half).
  const int srow = lane >> 3;                    // row within 8-row block
  const int schunk = ((lane & 7) ^ srow) * 8;    // pre-swizzled source chunk
  const u16* apt[2][2]; const u16* bpt[2][2];
  int aoff[2][2], boff[2][2];
#pragma unroll
  for (int h = 0; h < 2; ++h)
#pragma unroll
    for (int i = 0; i < 2; ++i) {
      int idx = wave * 2 + i;
      int rba = (idx & 7) + (idx >> 3) * 16 + h * 8;   // A rowblocks
      int rbb = (idx & 3) + (idx >> 2) * 8 + h * 4;    // B rowblocks
      apt[h][i] = A + (size_t)(m0 + rba * 8 + srow) * HID + schunk;
      bpt[h][i] = B + (size_t)(n0 + rbb * 8 + srow) * HID + schunk;
      aoff[h][i] = rba * 512;
      boff[h][i] = rbb * 512;
    }

  // prologue: Al(0) Bl(0) Bh(0) Ah(0) Al(1) Bh(1) Ah(1); keep last 3 in flight.
  SGA(0, 0, 0); SGB(0, 0, 0); SGB(0, 1, 0); SGA(0, 1, 0);
  SGA(1, 0, 1); SGB(1, 1, 1); SGA(1, 1, 1);
  SB0;
  VM6;
  __builtin_amdgcn_s_barrier();

  short8 af[4][2];
  short8 bfr[2][2];
  for (int j = 0; j < 64; j += 2) {
    const int s2 = (j + 2 < 63) ? j + 2 : 63;
    const int s3 = (j + 3 < 63) ? j + 3 : 63;
    // block j (buf0): quadrants (0,0),(0,1),(1,1),(1,0)
    PH(0, 0, 0, 1, 1, SGB(1, 0, j + 1), LG8,     (void)0);  // stage Bl(j+1)->buf1
    PH(0, 0, 1, 0, 1, SGA(0, 0, s2),    (void)0, (void)0);  // stage Al(j+2)->buf0
    PH(0, 1, 1, 1, 0, SGB(0, 1, s2),    (void)0, (void)0);  // stage Bh(j+2)->buf0
    PH(0, 1, 0, 0, 1, SGA(0, 1, s2),    (void)0, VM6);      // stage Ah(j+2)->buf0
    // block j+1 (buf1)
    PH(1, 0, 0, 1, 1, SGB(0, 0, s2),    LG8,     (void)0);  // stage Bl(j+2)->buf0
    PH(1, 0, 1, 0, 1, SGA(1, 0, s3),    (void)0, (void)0);  // stage Al(j+3)->buf1
    PH(1, 1, 1, 1, 0, SGB(1, 1, s3),    (void)0, (void)0);  // stage Bh(j+3)->buf1
    PH(1, 1, 0, 0, 1, SGA(1, 1, s3),    (void)0, VM6);      // stage Ah(j+3)->buf1
  }

  asm volatile("s_waitcnt vmcnt(0)" ::: "memory");  // drain tail dup-stages

  // C/D layout: row = lq*4 + r, col = lc
  if (n0 >= 5120) {  // V heads -> VT[kvh][d][t], 4 t packed
#pragma unroll
    for (int mi = 0; mi < 8; ++mi) {
      int row = m0 + wm * 128 + mi * 16 + lq * 4;
#pragma unroll
      for (int ni = 0; ni < 4; ++ni) {
        int rel = n0 + wn * 64 + ni * 16 + lc - 5120;
        ushort4 u;
        u.x = f2bf(acc[mi][ni][0]); u.y = f2bf(acc[mi][ni][1]);
        u.z = f2bf(acc[mi][ni][2]); u.w = f2bf(acc[mi][ni][3]);
        *(ushort4*)&VT[(size_t)rel * T_SEQ + row] = u;
      }
    }
  } else {
#pragma unroll
    for (int mi = 0; mi < 8; ++mi) {
      int row = m0 + wm * 128 + mi * 16 + lq * 4;
#pragma unroll
      for (int ni = 0; ni < 4; ++ni) {
        int col = n0 + wn * 64 + ni * 16 + lc;
#pragma unroll
        for (int r = 0; r < 4; ++r)
          C[(size_t)(row + r) * QKN + col] = f2bf(acc[mi][ni][r]);
      }
    }
  }
}

// ---------------------------------------------------------------- RMSNorm + RoPE
__global__ __launch_bounds__(256) void norm_rope_kernel(const u16* __restrict__ qk,
    const float* __restrict__ qw, const float* __restrict__ kw,
    u16* __restrict__ Qo, u16* __restrict__ Ko) {
  const int t = blockIdx.x;
  const int hs = blockIdx.y * 4 + (threadIdx.x >> 6);
  const int l = threadIdx.x & 63;
  const bool isq = hs < NH;
  const int col0 = isq ? hs * HD : QSZ + (hs - NH) * HD;
  const u16* src = qk + (size_t)t * QKN + col0;
  float x1 = bf2f(src[l]);
  float x2 = bf2f(src[l + 64]);
  float ss = x1 * x1 + x2 * x2;
#pragma unroll
  for (int m = 1; m < 64; m <<= 1) ss += __shfl_xor(ss, m);
  float rstd = rsqrtf(ss * (1.0f / HD) + 1e-6f);
  const float* w = isq ? qw : kw;
  float n1 = x1 * rstd * w[l];
  float n2 = x2 * rstd * w[l + 64];
  float inv = exp2f((float)l * -0.20762050593045158f);  // 10000^(-l/64)
  float ang = (float)t * inv;
  float s, c;
  __sincosf(ang, &s, &c);
  float o1 = n1 * c - n2 * s;
  float o2 = n2 * c + n1 * s;
  if (isq) {
    o1 *= 0.08838834764831845f; o2 *= 0.08838834764831845f;  // 1/sqrt(128)
    u16* dst = Qo + ((size_t)hs * T_SEQ + t) * HD;
    dst[l] = f2bf(o1); dst[l + 64] = f2bf(o2);
  } else {
    u16* dst = Ko + ((size_t)(hs - NH) * T_SEQ + t) * HD;
    dst[l] = f2bf(o1); dst[l + 64] = f2bf(o2);
  }
}

// ---------------------------------------------------------------- flash attention
// (unchanged — not in top-5; revisit once GEMM1 is fixed)
__global__ __launch_bounds__(256, 2) void attn_kernel(const u16* __restrict__ Qg,
    const u16* __restrict__ Kg, const u16* __restrict__ VTg, u16* __restrict__ Og) {
  __shared__ __attribute__((aligned(16))) u16 Ks[8192];
  __shared__ __attribute__((aligned(16))) u16 Vs[2][8192];
  __shared__ __attribute__((aligned(16))) u16 Ps[8192];

  const int bid = blockIdx.x;
  const int h = bid & 31;
  const int qq = bid >> 5;
  const int qt = (qq < 8) ? (15 - qq) : (qq - 8);
  const int kvh = h >> 2;
  const int tid = threadIdx.x;
  const int wave = tid >> 6, lane = tid & 63;
  const int lq = lane >> 4, lc = lane & 15;

  const u16* kbase[4];
  const u16* vbase[4];
#pragma unroll
  for (int i = 0; i < 4; ++i) {
    int L = i * 256 + tid;
    int s = L >> 4, cp = L & 15;
    kbase[i] = Kg + ((size_t)kvh * T_SEQ + s) * HD + ((cp ^ (s & 15)) * 8);
    int d = L >> 3, cv = L & 7;
    vbase[i] = VTg + ((size_t)kvh * HD + d) * T_SEQ + ((cv ^ (d & 7)) * 8);
  }

  short8 qf[2][4];
#pragma unroll
  for (int mb = 0; mb < 2; ++mb)
#pragma unroll
    for (int ks = 0; ks < 4; ++ks) {
      int t = qt * 128 + wave * 32 + mb * 16 + lc;
      qf[mb][ks] = *(const short8*)&Qg[((size_t)h * T_SEQ + t) * HD + ks * 32 + lq * 8];
    }

  short8 ones;
#pragma unroll
  for (int j = 0; j < 8; ++j) ones[j] = (short)0x3F80;  // bf16 1.0

  floatx4 of[2][8];
  floatx4 lacc[2];
#pragma unroll
  for (int mb = 0; mb < 2; ++mb) {
    lacc[mb] = {0.f, 0.f, 0.f, 0.f};
#pragma unroll
    for (int db = 0; db < 8; ++db) of[mb][db] = {0.f, 0.f, 0.f, 0.f};
  }

  const int ktmax = 2 * qt + 1;
  const int t0g = qt * 128 + wave * 32;
  const int wave_tmax = t0g + 31;

#pragma unroll
  for (int i = 0; i < 4; ++i) {
    GLD16(kbase[i], Ks + (i * 256 + wave * 64) * 8);
    GLD16(vbase[i], Vs[0] + (i * 256 + wave * 64) * 8);
  }

  for (int kt = 0; kt <= ktmax; ++kt) {
    __syncthreads();
    if (kt + 1 <= ktmax) {
      u16* vd = Vs[(kt + 1) & 1] + (size_t)wave * 64 * 8;
#pragma unroll
      for (int i = 0; i < 4; ++i)
        GLD16(vbase[i] + (kt + 1) * 64, vd + i * 256 * 8);
    }
    const bool active = (kt * 64) <= wave_tmax;
    if (active) {
      floatx4 sf[2][4];
#pragma unroll
      for (int mb = 0; mb < 2; ++mb)
#pragma unroll
        for (int nb = 0; nb < 4; ++nb) sf[mb][nb] = {0.f, 0.f, 0.f, 0.f};
#pragma unroll
      for (int ks = 0; ks < 4; ++ks) {
        short8 kf[4];
#pragma unroll
        for (int nb = 0; nb < 4; ++nb)
          kf[nb] = *(const short8*)&Ks[(nb * 16 + lc) * 128 + ((4 * ks + lq) ^ lc) * 8];
#pragma unroll
        for (int mb = 0; mb < 2; ++mb)
#pragma unroll
          for (int nb = 0; nb < 4; ++nb)
            sf[mb][nb] = mfma16(kf[nb], qf[mb][ks], sf[mb][nb]);
      }
      const bool nm = (kt * 64 + 63) > t0g;
#pragma unroll
      for (int mb = 0; mb < 2; ++mb) {
        const int trow = wave * 32 + mb * 16 + lc;
        const int tg = qt * 128 + trow;
#pragma unroll
        for (int nb = 0; nb < 4; ++nb) {
          ushort4 u;
          float p0 = __expf(sf[mb][nb][0]);
          float p1 = __expf(sf[mb][nb][1]);
          float p2 = __expf(sf[mb][nb][2]);
          float p3 = __expf(sf[mb][nb][3]);
          if (nm) {
            int sg = kt * 64 + nb * 16 + lq * 4;
            p0 = (sg + 0 <= tg) ? p0 : 0.f;
            p1 = (sg + 1 <= tg) ? p1 : 0.f;
            p2 = (sg + 2 <= tg) ? p2 : 0.f;
            p3 = (sg + 3 <= tg) ? p3 : 0.f;
          }
          u.x = f2bf(p0); u.y = f2bf(p1); u.z = f2bf(p2); u.w = f2bf(p3);
          int c = 2 * nb + (lq >> 1);
          *(ushort4*)&Ps[trow * 64 + ((c ^ (trow & 7)) * 8) + (lq & 1) * 4] = u;
        }
      }
    }
    __syncthreads();
    if (kt + 1 <= ktmax) {
      u16* kd = Ks + (size_t)wave * 64 * 8;
#pragma unroll
      for (int i = 0; i < 4; ++i)
        GLD16(kbase[i] + (size_t)(kt + 1) * 8192, kd + i * 256 * 8);
    }
    if (active) {
      const u16* vb = Vs[kt & 1];
      short8 pf[2][2];
#pragma unroll
      for (int mb = 0; mb < 2; ++mb)
#pragma unroll
        for (int k2 = 0; k2 < 2; ++k2) {
          int trow = wave * 32 + mb * 16 + lc;
          pf[mb][k2] =
              *(const short8*)&Ps[trow * 64 + (((4 * k2 + lq) ^ (lc & 7)) * 8)];
        }
#pragma unroll
      for (int k2 = 0; k2 < 2; ++k2) {
#pragma unroll
        for (int db = 0; db < 8; ++db) {
          short8 vf =
              *(const short8*)&vb[(db * 16 + lc) * 64 + (((4 * k2 + lq) ^ (lc & 7)) * 8)];
          of[0][db] = mfma16(pf[0][k2], vf, of[0][db]);
          of[1][db] = mfma16(pf[1][k2], vf, of[1][db]);
        }
        lacc[0] = mfma16(pf[0][k2], ones, lacc[0]);
        lacc[1] = mfma16(pf[1][k2], ones, lacc[1]);
      }
    }
  }
#pragma unroll
  for (int mb = 0; mb < 2; ++mb)
#pragma unroll
    for (int r = 0; r < 4; ++r) {
      float inv = 1.f / lacc[mb][r];
      int tg = qt * 128 + wave * 32 + mb * 16 + lq * 4 + r;
#pragma unroll
      for (int db = 0; db < 8; ++db)
        Og[(size_t)tg * QSZ + h * HD + db * 16 + lc] = f2bf(of[mb][db][r] * inv);
    }
}

// ---------------------------------------------------------------- launcher
extern "C" void kernel_launch(void* const* d_in, const int* in_sizes, int n_in,
                              void* d_out, int out_size, void* d_ws, size_t ws_size,
                              hipStream_t stream) {
  (void)in_sizes; (void)n_in; (void)out_size; (void)ws_size;
  const float* hidden = (const float*)d_in[1];
  const float* wqkv   = (const float*)d_in[2];
  const float* wo     = (const float*)d_in[3];
  const float* qw     = (const float*)d_in[4];
  const float* kw     = (const float*)d_in[5];
  float* out = (float*)d_out;
  char* ws = (char*)d_ws;

  u16* h_bf    = (u16*)(ws + 0);
  u16* wq_bf   = (u16*)(ws + 16777216);
  u16* wo_bf   = (u16*)(ws + 67108864);
  u16* vT_bf   = (u16*)(ws + 100663296);
  u16* qk_bf   = (u16*)(ws + 104857600);
  u16* q_bf    = (u16*)(ws + 16777216);
  u16* k_bf    = (u16*)(ws + 33554432);
  u16* attn_bf = (u16*)(ws + 0);

  cvt3_kernel<<<8192, 256, 0, stream>>>(
      hidden, wqkv, wo, h_bf, wq_bf, wo_bf,
      T_SEQ * HID / 4, QKVN * HID / 4, HID * QSZ / 4);

  gemm1_8ph<<<192, 512, 0, stream>>>(h_bf, wq_bf, qk_bf, vT_bf);

  norm_rope_kernel<<<dim3(T_SEQ, 10), 256, 0, stream>>>(
      qk_bf, qw, kw, q_bf, k_bf);

  attn_kernel<<<512, 256, 0, stream>>>(q_bf, k_bf, vT_bf, attn_bf);

  gemm_bt<0><<<512, 256, 0, stream>>>(attn_bf, wo_bf, out, vT_bf,
                                      T_SEQ / 128, HID, QSZ);
}

// Round 4
// 471.844 us; speedup vs baseline: 1.1318x; 1.1214x over previous
//
#include <hip/hip_runtime.h>

// Dots1Attention on MI355X (gfx950).
// cvt3(fp32->bf16, fused, 32B/lane) -> GEMM1(qkv, 128^2 m97-structure; V
//   written transposed in epilogue) -> rmsnorm+rope (1 block/t, hoisted trig)
//   -> flash attention (MFMA, no-max softmax) -> GEMM2(128^2).
// R1/R2 note: the 256^2 8-phase GEMM template measured 626 TF (MfmaUtil 25%)
// with and without sched_barrier pins — the counted-vmcnt overlap does not
// reproduce at source level here (m232's open quadrant). Reverted to the 128^2
// 2-barrier structure, which runs at its documented ~970 TF ceiling.
// R3 bench was an infra failure (container died twice); this is an identical
// resubmit of the R3 source to get its measurement.

#define T_SEQ 2048
#define HID   4096
#define NH    32
#define NKVH  8
#define HD    128
#define QKVN  6144
#define QSZ   4096
#define QKN   5120   // qk buffer row stride (V not stored row-major)

typedef unsigned short u16;
typedef __attribute__((ext_vector_type(8))) short short8;
typedef __attribute__((ext_vector_type(4))) float floatx4;

__device__ __forceinline__ float bf2f(u16 u) {
  union { unsigned int i; float f; } c; c.i = ((unsigned int)u) << 16; return c.f;
}
__device__ __forceinline__ u16 f2bf(float f) {
  union { float f; unsigned int i; } c; c.f = f;
  unsigned int u = c.i;
  return (u16)((u + 0x7FFFu + ((u >> 16) & 1u)) >> 16);  // RNE
}
__device__ __forceinline__ floatx4 mfma16(short8 a, short8 b, floatx4 c) {
  return __builtin_amdgcn_mfma_f32_16x16x32_bf16(a, b, c, 0, 0, 0);
}

#define GLD16(g, l) __builtin_amdgcn_global_load_lds( \
    (__attribute__((address_space(1))) unsigned int*)(g), \
    (__attribute__((address_space(3))) unsigned int*)(l), 16, 0, 0)

// ---------------------------------------------------------------- cvt f32->bf16 x3
// 8 floats per lane per step: 2x float4 read (32B), 1x uint4 write (16B).
// n0/n1/n2 are in 8-float groups.
__global__ __launch_bounds__(256) void cvt3_kernel(
    const float* __restrict__ s0, const float* __restrict__ s1,
    const float* __restrict__ s2, u16* __restrict__ d0, u16* __restrict__ d1,
    u16* __restrict__ d2, int n0, int n1, int n2) {
  int total = n0 + n1 + n2;
  int stride = gridDim.x * 256;
  for (int i = blockIdx.x * 256 + threadIdx.x; i < total; i += stride) {
    const float* s; u16* d; int j = i;
    if (j < n0)           { s = s0; d = d0; }
    else if (j < n0 + n1) { j -= n0; s = s1; d = d1; }
    else                  { j -= n0 + n1; s = s2; d = d2; }
    float4 a = ((const float4*)s)[2 * j];
    float4 b = ((const float4*)s)[2 * j + 1];
    union { ushort u[8]; uint4 v; } o;
    o.u[0] = f2bf(a.x); o.u[1] = f2bf(a.y); o.u[2] = f2bf(a.z); o.u[3] = f2bf(a.w);
    o.u[4] = f2bf(b.x); o.u[5] = f2bf(b.y); o.u[6] = f2bf(b.z); o.u[7] = f2bf(b.w);
    ((uint4*)d)[j] = o.v;
  }
}

// ---------------------------------------------------------------- GEMM  C = A * B^T
// A[M][K], B[N][K] bf16 row-major. 128x128 tile, BK=64, 4 waves x 64x64.
// LDS layout: per 128-row tile, row m has 8 chunks of 8 bf16; logical chunk c
// lives at physical slot c ^ (m&7). Bank-uniform for GLD16 + ds_read_b128
// (0 conflicts measured). MODE 0: f32 C. MODE 1: bf16 C for cols < 5120;
// cols >= 5120 are V heads, written transposed to VT[kvh][d][t].
template <int MODE>
__global__ __launch_bounds__(256, 2) void gemm_bt(const u16* __restrict__ A,
    const u16* __restrict__ B, void* __restrict__ Cv, u16* __restrict__ VT,
    int mtiles, int K, int ldC) {
  __shared__ __attribute__((aligned(16))) u16 As[128 * 64];
  __shared__ __attribute__((aligned(16))) u16 Bs[128 * 64];
  const int tid = threadIdx.x;
  const int wave = tid >> 6, lane = tid & 63;
  const int lq = lane >> 4, lc = lane & 15;
  const int wm = wave >> 1, wn = wave & 1;
  // XCD-aware bijective swizzle (grid % 8 == 0), then col-major decompose
  // (consecutive ids share the B tile -> per-XCD L2 locality).
  const int id = ((int)blockIdx.x & 7) * ((int)gridDim.x >> 3) + ((int)blockIdx.x >> 3);
  const int by = id % mtiles, bx = id / mtiles;
  const int m0 = by * 128, n0 = bx * 128;

  floatx4 acc[4][4];
#pragma unroll
  for (int i = 0; i < 4; ++i)
#pragma unroll
    for (int j = 0; j < 4; ++j) acc[i][j] = {0.f, 0.f, 0.f, 0.f};

  int arow[4], brow[4];
#pragma unroll
  for (int i = 0; i < 4; ++i) {
    arow[i] = wm * 64 + i * 16 + lc;
    brow[i] = wn * 64 + i * 16 + lc;
  }

  const u16* asrc[4]; const u16* bsrc[4];
#pragma unroll
  for (int r = 0; r < 4; ++r) {
    int L = r * 256 + tid;
    int mm = L >> 3;
    int cc = (L & 7) ^ (mm & 7);
    asrc[r] = A + (size_t)(m0 + mm) * K + cc * 8;
    bsrc[r] = B + (size_t)(n0 + mm) * K + cc * 8;
  }

  for (int k0 = 0; k0 < K; k0 += 64) {
#pragma unroll
    for (int r = 0; r < 4; ++r) {
      GLD16(asrc[r] + k0, As + (r * 256 + wave * 64) * 8);
      GLD16(bsrc[r] + k0, Bs + (r * 256 + wave * 64) * 8);
    }
    __syncthreads();
#pragma unroll
    for (int kb = 0; kb < 2; ++kb) {
      short8 af[4], bfr[4];
#pragma unroll
      for (int mi = 0; mi < 4; ++mi)
        af[mi] = *(const short8*)&As[arow[mi] * 64 + (((kb * 4 + lq) ^ (arow[mi] & 7)) * 8)];
#pragma unroll
      for (int ni = 0; ni < 4; ++ni)
        bfr[ni] = *(const short8*)&Bs[brow[ni] * 64 + (((kb * 4 + lq) ^ (brow[ni] & 7)) * 8)];
#pragma unroll
      for (int mi = 0; mi < 4; ++mi)
#pragma unroll
        for (int ni = 0; ni < 4; ++ni)
          acc[mi][ni] = mfma16(af[mi], bfr[ni], acc[mi][ni]);
    }
    __syncthreads();
  }

  // C/D layout: row = lq*4 + r, col = lc (m89/m91-verified)
  if (MODE == 1 && n0 >= 5120) {  // V heads -> VT[kvh][d][t], 4 t packed
#pragma unroll
    for (int mi = 0; mi < 4; ++mi) {
      int row = m0 + wm * 64 + mi * 16 + lq * 4;  // t, multiple of 4
#pragma unroll
      for (int ni = 0; ni < 4; ++ni) {
        int rel = n0 + wn * 64 + ni * 16 + lc - 5120;
        ushort4 u;
        u.x = f2bf(acc[mi][ni][0]); u.y = f2bf(acc[mi][ni][1]);
        u.z = f2bf(acc[mi][ni][2]); u.w = f2bf(acc[mi][ni][3]);
        *(ushort4*)&VT[(size_t)rel * T_SEQ + row] = u;  // rel = kvh*128 + d
      }
    }
  } else {
#pragma unroll
    for (int mi = 0; mi < 4; ++mi) {
      int row = m0 + wm * 64 + mi * 16 + lq * 4;
#pragma unroll
      for (int ni = 0; ni < 4; ++ni) {
        int col = n0 + wn * 64 + ni * 16 + lc;
#pragma unroll
        for (int r = 0; r < 4; ++r) {
          if (MODE == 1)
            ((u16*)Cv)[(size_t)(row + r) * ldC + col] = f2bf(acc[mi][ni][r]);
          else
            ((float*)Cv)[(size_t)(row + r) * ldC + col] = acc[mi][ni][r];
        }
      }
    }
  }
}

// ---------------------------------------------------------------- RMSNorm + RoPE
// grid (T), block 256: wave w loops head-slots w, w+4, ..., w+36 (0..31 q,
// 32..39 k). Lane l owns dims l, l+64 (the RoPE rotate pair). Angle and
// weights depend only on (t,l) / (l) -> hoisted out of the slot loop.
// Q also scaled by 1/sqrt(HD).
__global__ __launch_bounds__(256) void norm_rope_kernel(const u16* __restrict__ qk,
    const float* __restrict__ qw, const float* __restrict__ kw,
    u16* __restrict__ Qo, u16* __restrict__ Ko) {
  const int t = blockIdx.x;
  const int w = threadIdx.x >> 6;
  const int l = threadIdx.x & 63;
  const float inv = exp2f((float)l * -0.20762050593045158f);  // 10000^(-l/64)
  float s, c;
  __sincosf((float)t * inv, &s, &c);
  const float qwl = qw[l], qwh = qw[l + 64];
  const float kwl = kw[l], kwh = kw[l + 64];
  const u16* row = qk + (size_t)t * QKN;
#pragma unroll 2
  for (int hs = w; hs < NH + NKVH; hs += 4) {
    const bool isq = hs < NH;
    const u16* src = row + hs * HD;
    float x1 = bf2f(src[l]);
    float x2 = bf2f(src[l + 64]);
    float ss = x1 * x1 + x2 * x2;
#pragma unroll
    for (int m = 1; m < 64; m <<= 1) ss += __shfl_xor(ss, m);
    float rstd = rsqrtf(ss * (1.0f / HD) + 1e-6f);
    float n1 = x1 * rstd * (isq ? qwl : kwl);
    float n2 = x2 * rstd * (isq ? qwh : kwh);
    float o1 = n1 * c - n2 * s;
    float o2 = n2 * c + n1 * s;
    if (isq) {
      o1 *= 0.08838834764831845f; o2 *= 0.08838834764831845f;  // 1/sqrt(128)
      u16* dst = Qo + ((size_t)hs * T_SEQ + t) * HD;
      dst[l] = f2bf(o1); dst[l + 64] = f2bf(o2);
    } else {
      u16* dst = Ko + ((size_t)(hs - NH) * T_SEQ + t) * HD;
      dst[l] = f2bf(o1); dst[l + 64] = f2bf(o2);
    }
  }
}

// ---------------------------------------------------------------- flash attention
// (unchanged — hidden below GEMM1 in top-5; target next round if the residual
// arithmetic says it is large)
__global__ __launch_bounds__(256, 2) void attn_kernel(const u16* __restrict__ Qg,
    const u16* __restrict__ Kg, const u16* __restrict__ VTg, u16* __restrict__ Og) {
  __shared__ __attribute__((aligned(16))) u16 Ks[8192];
  __shared__ __attribute__((aligned(16))) u16 Vs[2][8192];
  __shared__ __attribute__((aligned(16))) u16 Ps[8192];

  const int bid = blockIdx.x;
  const int h = bid & 31;
  const int qq = bid >> 5;
  const int qt = (qq < 8) ? (15 - qq) : (qq - 8);
  const int kvh = h >> 2;
  const int tid = threadIdx.x;
  const int wave = tid >> 6, lane = tid & 63;
  const int lq = lane >> 4, lc = lane & 15;

  const u16* kbase[4];
  const u16* vbase[4];
#pragma unroll
  for (int i = 0; i < 4; ++i) {
    int L = i * 256 + tid;
    int s = L >> 4, cp = L & 15;
    kbase[i] = Kg + ((size_t)kvh * T_SEQ + s) * HD + ((cp ^ (s & 15)) * 8);
    int d = L >> 3, cv = L & 7;
    vbase[i] = VTg + ((size_t)kvh * HD + d) * T_SEQ + ((cv ^ (d & 7)) * 8);
  }

  short8 qf[2][4];
#pragma unroll
  for (int mb = 0; mb < 2; ++mb)
#pragma unroll
    for (int ks = 0; ks < 4; ++ks) {
      int t = qt * 128 + wave * 32 + mb * 16 + lc;
      qf[mb][ks] = *(const short8*)&Qg[((size_t)h * T_SEQ + t) * HD + ks * 32 + lq * 8];
    }

  short8 ones;
#pragma unroll
  for (int j = 0; j < 8; ++j) ones[j] = (short)0x3F80;  // bf16 1.0

  floatx4 of[2][8];
  floatx4 lacc[2];
#pragma unroll
  for (int mb = 0; mb < 2; ++mb) {
    lacc[mb] = {0.f, 0.f, 0.f, 0.f};
#pragma unroll
    for (int db = 0; db < 8; ++db) of[mb][db] = {0.f, 0.f, 0.f, 0.f};
  }

  const int ktmax = 2 * qt + 1;
  const int t0g = qt * 128 + wave * 32;
  const int wave_tmax = t0g + 31;

#pragma unroll
  for (int i = 0; i < 4; ++i) {
    GLD16(kbase[i], Ks + (i * 256 + wave * 64) * 8);
    GLD16(vbase[i], Vs[0] + (i * 256 + wave * 64) * 8);
  }

  for (int kt = 0; kt <= ktmax; ++kt) {
    __syncthreads();
    if (kt + 1 <= ktmax) {
      u16* vd = Vs[(kt + 1) & 1] + (size_t)wave * 64 * 8;
#pragma unroll
      for (int i = 0; i < 4; ++i)
        GLD16(vbase[i] + (kt + 1) * 64, vd + i * 256 * 8);
    }
    const bool active = (kt * 64) <= wave_tmax;
    if (active) {
      floatx4 sf[2][4];
#pragma unroll
      for (int mb = 0; mb < 2; ++mb)
#pragma unroll
        for (int nb = 0; nb < 4; ++nb) sf[mb][nb] = {0.f, 0.f, 0.f, 0.f};
#pragma unroll
      for (int ks = 0; ks < 4; ++ks) {
        short8 kf[4];
#pragma unroll
        for (int nb = 0; nb < 4; ++nb)
          kf[nb] = *(const short8*)&Ks[(nb * 16 + lc) * 128 + ((4 * ks + lq) ^ lc) * 8];
#pragma unroll
        for (int mb = 0; mb < 2; ++mb)
#pragma unroll
          for (int nb = 0; nb < 4; ++nb)
            sf[mb][nb] = mfma16(kf[nb], qf[mb][ks], sf[mb][nb]);
      }
      const bool nm = (kt * 64 + 63) > t0g;
#pragma unroll
      for (int mb = 0; mb < 2; ++mb) {
        const int trow = wave * 32 + mb * 16 + lc;
        const int tg = qt * 128 + trow;
#pragma unroll
        for (int nb = 0; nb < 4; ++nb) {
          ushort4 u;
          float p0 = __expf(sf[mb][nb][0]);
          float p1 = __expf(sf[mb][nb][1]);
          float p2 = __expf(sf[mb][nb][2]);
          float p3 = __expf(sf[mb][nb][3]);
          if (nm) {
            int sg = kt * 64 + nb * 16 + lq * 4;
            p0 = (sg + 0 <= tg) ? p0 : 0.f;
            p1 = (sg + 1 <= tg) ? p1 : 0.f;
            p2 = (sg + 2 <= tg) ? p2 : 0.f;
            p3 = (sg + 3 <= tg) ? p3 : 0.f;
          }
          u.x = f2bf(p0); u.y = f2bf(p1); u.z = f2bf(p2); u.w = f2bf(p3);
          int c = 2 * nb + (lq >> 1);
          *(ushort4*)&Ps[trow * 64 + ((c ^ (trow & 7)) * 8) + (lq & 1) * 4] = u;
        }
      }
    }
    __syncthreads();
    if (kt + 1 <= ktmax) {
      u16* kd = Ks + (size_t)wave * 64 * 8;
#pragma unroll
      for (int i = 0; i < 4; ++i)
        GLD16(kbase[i] + (size_t)(kt + 1) * 8192, kd + i * 256 * 8);
    }
    if (active) {
      const u16* vb = Vs[kt & 1];
      short8 pf[2][2];
#pragma unroll
      for (int mb = 0; mb < 2; ++mb)
#pragma unroll
        for (int k2 = 0; k2 < 2; ++k2) {
          int trow = wave * 32 + mb * 16 + lc;
          pf[mb][k2] =
              *(const short8*)&Ps[trow * 64 + (((4 * k2 + lq) ^ (lc & 7)) * 8)];
        }
#pragma unroll
      for (int k2 = 0; k2 < 2; ++k2) {
#pragma unroll
        for (int db = 0; db < 8; ++db) {
          short8 vf =
              *(const short8*)&vb[(db * 16 + lc) * 64 + (((4 * k2 + lq) ^ (lc & 7)) * 8)];
          of[0][db] = mfma16(pf[0][k2], vf, of[0][db]);
          of[1][db] = mfma16(pf[1][k2], vf, of[1][db]);
        }
        lacc[0] = mfma16(pf[0][k2], ones, lacc[0]);
        lacc[1] = mfma16(pf[1][k2], ones, lacc[1]);
      }
    }
  }
#pragma unroll
  for (int mb = 0; mb < 2; ++mb)
#pragma unroll
    for (int r = 0; r < 4; ++r) {
      float inv = 1.f / lacc[mb][r];
      int tg = qt * 128 + wave * 32 + mb * 16 + lq * 4 + r;
#pragma unroll
      for (int db = 0; db < 8; ++db)
        Og[(size_t)tg * QSZ + h * HD + db * 16 + lc] = f2bf(of[mb][db][r] * inv);
    }
}

// ---------------------------------------------------------------- launcher
extern "C" void kernel_launch(void* const* d_in, const int* in_sizes, int n_in,
                              void* d_out, int out_size, void* d_ws, size_t ws_size,
                              hipStream_t stream) {
  (void)in_sizes; (void)n_in; (void)out_size; (void)ws_size;
  const float* hidden = (const float*)d_in[1];
  const float* wqkv   = (const float*)d_in[2];
  const float* wo     = (const float*)d_in[3];
  const float* qw     = (const float*)d_in[4];
  const float* kw     = (const float*)d_in[5];
  float* out = (float*)d_out;
  char* ws = (char*)d_ws;

  // workspace (lifetime-aliased):
  //  [0,16M)    h_bf (dead after GEMM1)  -> attn_bf
  //  [16M,64M)  wq_bf (dead after GEMM1) -> q_bf [16M,32M), k_bf [32M,36M)
  //  [64M,96M)  wo_bf (persists to GEMM2)
  //  [96M,100M) vT_bf (written by GEMM1 epilogue)
  //  [100M,120M) qk_bf (dead after norm_rope)
  u16* h_bf    = (u16*)(ws + 0);
  u16* wq_bf   = (u16*)(ws + 16777216);
  u16* wo_bf   = (u16*)(ws + 67108864);
  u16* vT_bf   = (u16*)(ws + 100663296);
  u16* qk_bf   = (u16*)(ws + 104857600);
  u16* q_bf    = (u16*)(ws + 16777216);
  u16* k_bf    = (u16*)(ws + 33554432);
  u16* attn_bf = (u16*)(ws + 0);

  cvt3_kernel<<<4096, 256, 0, stream>>>(
      hidden, wqkv, wo, h_bf, wq_bf, wo_bf,
      T_SEQ * HID / 8, QKVN * HID / 8, HID * QSZ / 8);

  gemm_bt<1><<<768, 256, 0, stream>>>(h_bf, wq_bf, qk_bf, vT_bf,
                                      T_SEQ / 128, HID, QKN);

  norm_rope_kernel<<<T_SEQ, 256, 0, stream>>>(qk_bf, qw, kw, q_bf, k_bf);

  attn_kernel<<<512, 256, 0, stream>>>(q_bf, k_bf, vT_bf, attn_bf);

  gemm_bt<0><<<512, 256, 0, stream>>>(attn_bf, wo_bf, out, vT_bf,
                                      T_SEQ / 128, HID, QSZ);
}